// Round 2
// baseline (1667.637 us; speedup 1.0000x reference)
//
#include <hip/hip_runtime.h>
#include <math.h>

#define N_NODES 100000
#define N_EDGES 3200000
#define DIM 256
#define SCAN_B 1024
#define NPASS 8
#define WIN ((N_NODES + NPASS - 1) / NPASS)  // 12500

// src-window bucketing for the aggregate gather
#define WSH 12                       // window = src >> 12 (4096 nodes = 2.1 MB of xw)
#define NW 25                        // ceil(100000/4096)
#define NBUCK (NW * N_NODES)         // 2,500,000 (window-major: [w][dst])
#define SCAN_GRID_W ((NBUCK + SCAN_B - 1) / SCAN_B)  // 2442

// aggregate geometry: wave owns NPW consecutive nodes, f32 accum in VGPRs
#define NPW 12
#define NPB (4 * NPW)                // nodes per block (4 waves)
#define AGG_GRID ((N_NODES + NPB - 1) / NPB)  // 2084

typedef unsigned short u16;
typedef unsigned int u32;
typedef __attribute__((ext_vector_type(8))) short bf16x8;
typedef __attribute__((ext_vector_type(4))) float f32x4;

__device__ __forceinline__ float bf2f(u16 u) {
    union { u32 i; float f; } v; v.i = ((u32)u) << 16; return v.f;
}
__device__ __forceinline__ u16 f2bf(float f) {
    union { float f; u32 i; } v; v.f = f;
    u32 x = v.i;
    return (u16)((x + 0x7fffu + ((x >> 16) & 1u)) >> 16);
}
__device__ __forceinline__ float sane(float v) {
    union { float f; u32 i; } u; u.f = v;
    if ((u.i & 0x7f800000u) == 0x7f800000u) return 0.f;
    return v;
}
__device__ __forceinline__ int iclamp(int v, int lo, int hi) {
    return v < lo ? lo : (v > hi ? hi : v);
}
// one dword holding 2 bf16 -> float2 (lo elem, hi elem)
__device__ __forceinline__ float2 cvt2(u32 d) {
    union { u32 i; float f; } lo, hi;
    lo.i = d << 16;
    hi.i = d & 0xffff0000u;
    return make_float2(lo.f, hi.f);
}

// ---- runtime format probes ----------------------------------------------
// flags[0]: 1 => float tensors are fp32, 0 => bf16
// flags[1]: 1 => edge_index is int64 (lo/hi word pairs), 0 => int32
__global__ void detect_kernel(const u32* __restrict__ xw_words,
                              const int* __restrict__ ei, int* __restrict__ flags) {
    int lane = threadIdx.x;
    int cnt = 0;
#pragma unroll
    for (int j = 0; j < 4; ++j) {
        u32 e = (xw_words[lane + 64 * j] >> 7) & 0xffu;
        cnt += (e >= 0x70 && e <= 0x88) ? 1 : 0;
    }
    int nz = 0;
#pragma unroll
    for (int j = 0; j < 4; ++j) nz += (ei[2 * (lane + 64 * j) + 1] != 0) ? 1 : 0;
#pragma unroll
    for (int off = 32; off; off >>= 1) {
        cnt += __shfl_down(cnt, off, 64);
        nz += __shfl_down(nz, off, 64);
    }
    if (lane == 0) {
        flags[0] = (cnt < 128) ? 1 : 0;
        flags[1] = (nz == 0) ? 1 : 0;
    }
}

__device__ __forceinline__ int edge_val(const int* __restrict__ ei, int which,
                                        int i, int f64) {
    long long idx = (long long)which * N_EDGES + i;
    int v = f64 ? ei[idx * 2] : ei[idx];
    return iclamp(v, 0, N_NODES - 1);
}

// ---- canonicalize x to internal bf16 ------------------------------------
__global__ void convert_x(const void* __restrict__ xin, u16* __restrict__ xbf,
                          const int* __restrict__ flags) {
    long long i = (long long)blockIdx.x * blockDim.x + threadIdx.x;
    if (i >= (long long)N_NODES * DIM) return;
    float v = flags[0] ? ((const float*)xin)[i] : bf2f(((const u16*)xin)[i]);
    xbf[i] = f2bf(sane(v));
}

// ---- bucket-CSR build: count per (src-window, dst) ----------------------
__global__ void count_convert(const int* __restrict__ ei, int* __restrict__ cntW,
                              int* __restrict__ src32, int* __restrict__ dst32,
                              const int* __restrict__ flags) {
    int i = blockIdx.x * blockDim.x + threadIdx.x;
    if (i < N_EDGES) {
        int f = flags[1];
        int s = edge_val(ei, 0, i, f);
        int d = edge_val(ei, 1, i, f);
        src32[i] = s;
        dst32[i] = d;
        int w = s >> WSH;
        atomicAdd(&cntW[w * N_NODES + d], 1);
    }
}

// dis from in-degree = sum of the node's bucket counts over windows
__global__ void deg_dis(const int* __restrict__ cntW, float* __restrict__ dis) {
    int i = blockIdx.x * blockDim.x + threadIdx.x;
    if (i < N_NODES) {
        int d = 0;
#pragma unroll
        for (int w = 0; w < NW; ++w) d += cntW[w * N_NODES + i];
        d = iclamp(d, 0, N_EDGES);
        dis[i] = rsqrtf((float)(d + 1));  // +1 self loop
    }
}

// ---- parallel 3-phase exclusive scan over NBUCK elements ----------------
__global__ __launch_bounds__(SCAN_B) void scan_block_sums(const int* __restrict__ cnt,
                                                          int* __restrict__ bsum,
                                                          int M) {
    __shared__ int ws[16];
    int i = blockIdx.x * SCAN_B + threadIdx.x;
    int v = (i < M) ? cnt[i] : 0;
#pragma unroll
    for (int off = 32; off; off >>= 1) v += __shfl_down(v, off, 64);
    if ((threadIdx.x & 63) == 0) ws[threadIdx.x >> 6] = v;
    __syncthreads();
    if (threadIdx.x < 16) {
        int t = ws[threadIdx.x];
#pragma unroll
        for (int off = 8; off; off >>= 1) t += __shfl_down(t, off, 16);
        if (threadIdx.x == 0) bsum[blockIdx.x] = t;
    }
}

// single-block scan of SCAN_GRID_W (=2442) block sums; 1024 thr x 3 elems
__global__ __launch_bounds__(1024) void scan_bsum_big(int* __restrict__ bsum) {
    __shared__ int sd[1024];
    int t = threadIdx.x;
    int base = t * 3;
    int v0 = (base     < SCAN_GRID_W) ? bsum[base]     : 0;
    int v1 = (base + 1 < SCAN_GRID_W) ? bsum[base + 1] : 0;
    int v2 = (base + 2 < SCAN_GRID_W) ? bsum[base + 2] : 0;
    int s = v0 + v1 + v2;
    sd[t] = s;
    __syncthreads();
    for (int off = 1; off < 1024; off <<= 1) {
        int x = (t >= off) ? sd[t - off] : 0;
        __syncthreads();
        sd[t] += x;
        __syncthreads();
    }
    int ex = sd[t] - s;  // exclusive prefix of this thread's 3-chunk
    if (base     < SCAN_GRID_W) bsum[base]     = ex;
    if (base + 1 < SCAN_GRID_W) bsum[base + 1] = ex + v0;
    if (base + 2 < SCAN_GRID_W) bsum[base + 2] = ex + v0 + v1;
}

__global__ __launch_bounds__(SCAN_B) void scan_final_w(const int* __restrict__ cnt,
                                                       const int* __restrict__ bsum,
                                                       int* __restrict__ rowptr,
                                                       int* __restrict__ cursor,
                                                       int M) {
    __shared__ int ws[16];
    int lane = threadIdx.x & 63;
    int wid = threadIdx.x >> 6;
    int i = blockIdx.x * SCAN_B + threadIdx.x;
    int c = (i < M) ? cnt[i] : 0;
    int v = c;
#pragma unroll
    for (int off = 1; off < 64; off <<= 1) {
        int t = __shfl_up(v, off, 64);
        if (lane >= off) v += t;
    }
    if (lane == 63) ws[wid] = v;
    __syncthreads();
    int woff = 0;
    for (int w = 0; w < wid; ++w) woff += ws[w];
    int excl = bsum[blockIdx.x] + woff + v - c;
    if (i < M) { rowptr[i] = excl; cursor[i] = excl; }
    if (blockIdx.x == 0 && threadIdx.x == 0) rowptr[M] = N_EDGES;
}

// ---- windowed CSR fill: pass p handles dst in [lo, lo+WIN) --------------
__global__ void fill_csr_pass(const int* __restrict__ src32,
                              const int* __restrict__ dst32,
                              int* __restrict__ cursorW, int* __restrict__ colidx,
                              int lo) {
    int i = blockIdx.x * blockDim.x + threadIdx.x;
    if (i < N_EDGES) {
        int d = dst32[i];
        if ((unsigned)(d - lo) < (unsigned)WIN) {
            int s = src32[i];
            int w = s >> WSH;
            int pos = atomicAdd(&cursorW[w * N_NODES + d], 1);
            colidx[pos] = s;
        }
    }
}

// ---- weight transpose (dtype-aware) -------------------------------------
__global__ void transpose_w(const void* __restrict__ W, u16* __restrict__ Wt,
                            const int* __restrict__ flags) {
    int n = blockIdx.x;
    int k = threadIdx.x;
    float v = flags[0] ? ((const float*)W)[k * DIM + n]
                       : bf2f(((const u16*)W)[k * DIM + n]);
    Wt[n * DIM + k] = f2bf(sane(v));
}

// ---- dense GEMM: register-resident B, dis-prescaled output --------------
// out[row] = bf16( dis[row] * (A[row] @ W) )
__global__ __launch_bounds__(256) void gemm_mfma(const u16* __restrict__ A,
                                                 const u16* __restrict__ Wt,
                                                 const float* __restrict__ dis,
                                                 u16* __restrict__ out) {
    int w = threadIdx.x >> 6;   // col-group 0..3
    int lane = threadIdx.x & 63;
    int rt = blockIdx.x;        // row tile (100000/16 = 6250 exact)
    int m = lane & 15;
    int quad = lane >> 4;

    bf16x8 B[4][8];
#pragma unroll
    for (int t2 = 0; t2 < 4; ++t2)
#pragma unroll
        for (int ks = 0; ks < 8; ++ks)
            B[t2][ks] = *(const bf16x8*)(Wt + (size_t)((w * 4 + t2) * 16 + m) * DIM +
                                         ks * 32 + quad * 8);

    const u16* arow = A + (size_t)(rt * 16 + m) * DIM + quad * 8;
    f32x4 acc[4];
#pragma unroll
    for (int t2 = 0; t2 < 4; ++t2) acc[t2] = (f32x4){0.f, 0.f, 0.f, 0.f};

#pragma unroll
    for (int ks = 0; ks < 8; ++ks) {
        bf16x8 a = *(const bf16x8*)(arow + ks * 32);
#pragma unroll
        for (int t2 = 0; t2 < 4; ++t2)
            acc[t2] = __builtin_amdgcn_mfma_f32_16x16x32_bf16(a, B[t2][ks], acc[t2], 0, 0, 0);
    }

    float4 dv = *(const float4*)(dis + rt * 16 + quad * 4);
    float dr[4] = {dv.x, dv.y, dv.z, dv.w};

#pragma unroll
    for (int t2 = 0; t2 < 4; ++t2) {
#pragma unroll
        for (int r = 0; r < 4; ++r) {
            int row = rt * 16 + quad * 4 + r;
            int c = w * 64 + t2 * 16 + m;
            out[(size_t)row * DIM + c] = f2bf(sane(acc[t2][r] * dr[r]));
        }
    }
}

// ---- windowed aggregation + bias + ELU ----------------------------------
// Edges bucketed by (src-window, dst); every wave sweeps windows 0..NW-1 in
// the same order, so the instantaneous gather working set is ~1 window
// (2.1 MB, XCD-L2 resident) instead of all 51.2 MB of xw.
// Wave owns NPW consecutive nodes; acc = NPW x 4 f32 VGPRs (static index).
// Lane holds cols [lane*4, lane*4+4): one uint2 (8B) gather = 512B row/wave.
__global__ __launch_bounds__(256, 4) void aggregate(const u16* __restrict__ xw,
                                                    const int* __restrict__ rowptrW,
                                                    const int* __restrict__ colidx,
                                                    const float* __restrict__ dis,
                                                    const void* __restrict__ bias,
                                                    void* __restrict__ out,
                                                    const int* __restrict__ flags,
                                                    int final_layer) {
    int wid = threadIdx.x >> 6;
    int lane = threadIdx.x & 63;
    int n0 = (blockIdx.x * 4 + wid) * NPW;
    const u16* xcol = xw + lane * 4;  // this lane's 4-col slice of any row

    f32x4 acc[NPW];
#pragma unroll
    for (int ln = 0; ln < NPW; ++ln) acc[ln] = (f32x4){0.f, 0.f, 0.f, 0.f};

    // self term (xw rows already carry dis[row])
#pragma unroll
    for (int ln = 0; ln < NPW; ++ln) {
        int n = n0 + ln;
        if (n < N_NODES) {
            uint2 v = *(const uint2*)(xcol + (size_t)n * DIM);
            float2 t0 = cvt2(v.x), t1 = cvt2(v.y);
            acc[ln][0] += t0.x; acc[ln][1] += t0.y;
            acc[ln][2] += t1.x; acc[ln][3] += t1.y;
        }
    }

    for (int w = 0; w < NW; ++w) {
        const int* pr = rowptrW + w * N_NODES;
        int pv = 0;
        if (lane <= NPW) {
            int idx = n0 + lane;
            if (idx > N_NODES) idx = N_NODES;
            pv = pr[idx];
        }
        int p[NPW], e[NPW];
#pragma unroll
        for (int ln = 0; ln < NPW; ++ln) {
            p[ln] = __builtin_amdgcn_readfirstlane(__shfl(pv, ln, 64));
            e[ln] = __builtin_amdgcn_readfirstlane(__shfl(pv, ln + 1, 64));
        }
        while (true) {
            int am = 0;
            uint2 v[NPW];
#pragma unroll
            for (int ln = 0; ln < NPW; ++ln) {
                if (p[ln] < e[ln]) {
                    int s = colidx[p[ln]];
                    v[ln] = *(const uint2*)(xcol + (size_t)s * DIM);
                    am |= 1 << ln;
                }
            }
            if (am == 0) break;
#pragma unroll
            for (int ln = 0; ln < NPW; ++ln) {
                if (am & (1 << ln)) {
                    ++p[ln];
                    float2 t0 = cvt2(v[ln].x), t1 = cvt2(v[ln].y);
                    acc[ln][0] += t0.x; acc[ln][1] += t0.y;
                    acc[ln][2] += t1.x; acc[ln][3] += t1.y;
                }
            }
        }
    }

    // epilogue: o = dis[node]*acc + bias, ELU, store
    int f32mode = flags[0];
    int c0 = lane * 4;
    float b0, b1, b2, b3;
    if (f32mode) {
        float4 bv = *(const float4*)((const float*)bias + c0);
        b0 = bv.x; b1 = bv.y; b2 = bv.z; b3 = bv.w;
    } else {
        ushort4 bv = *(const ushort4*)((const u16*)bias + c0);
        b0 = bf2f(bv.x); b1 = bf2f(bv.y); b2 = bf2f(bv.z); b3 = bf2f(bv.w);
    }
#pragma unroll
    for (int ln = 0; ln < NPW; ++ln) {
        int n = n0 + ln;
        if (n >= N_NODES) break;
        float dn = dis[n];
        float o0 = dn * acc[ln][0] + b0;
        float o1 = dn * acc[ln][1] + b1;
        float o2 = dn * acc[ln][2] + b2;
        float o3 = dn * acc[ln][3] + b3;
        o0 = sane(o0 > 0.f ? o0 : expm1f(o0));
        o1 = sane(o1 > 0.f ? o1 : expm1f(o1));
        o2 = sane(o2 > 0.f ? o2 : expm1f(o2));
        o3 = sane(o3 > 0.f ? o3 : expm1f(o3));
        if (final_layer && f32mode) {
            float4 ov; ov.x = o0; ov.y = o1; ov.z = o2; ov.w = o3;
            *(float4*)((float*)out + (size_t)n * DIM + c0) = ov;
        } else {
            ushort4 ov;
            ov.x = f2bf(o0); ov.y = f2bf(o1); ov.z = f2bf(o2); ov.w = f2bf(o3);
            *(ushort4*)((u16*)out + (size_t)n * DIM + c0) = ov;
        }
    }
}

// ---- launch -------------------------------------------------------------
extern "C" void kernel_launch(void* const* d_in, const int* in_sizes, int n_in,
                              void* d_out, int out_size, void* d_ws, size_t ws_size,
                              hipStream_t stream) {
    const void* x  = d_in[0];
    const int*  ei = (const int*)d_in[1];
    const void* W1 = d_in[2];
    const void* b1 = d_in[3];
    const void* W2 = d_in[4];
    const void* b2 = d_in[5];

    char* ws = (char*)d_ws;
    size_t off = 0;
    auto alloc = [&](size_t bytes) {
        void* p = ws + off;
        off = (off + bytes + 255) & ~(size_t)255;
        return p;
    };
    int*   flags   = (int*)alloc(256);
    int*   rowptrW = (int*)alloc(((size_t)NBUCK + 1) * 4);  // lives through aggregate
    int*   colidx  = (int*)alloc((size_t)N_EDGES * 4);
    float* dis     = (float*)alloc((size_t)N_NODES * 4);
    int*   bsum    = (int*)alloc((size_t)SCAN_GRID_W * 4 + 256);
    u16*   Wt      = (u16*)alloc((size_t)DIM * DIM * 2);
    u16*   xw      = (u16*)alloc((size_t)N_NODES * DIM * 2);  // 51.2 MB
    (void)ws_size;

    // CSR-build temporaries alias the xw region (all dead before gemm_mfma
    // first writes xw): src32 12.8MB | dst32 12.8MB | cntW 10MB | cursorW 10MB
    char* xwb = (char*)xw;
    int* src32   = (int*)xwb;
    int* dst32   = (int*)(xwb + (size_t)N_EDGES * 4);
    int* cntW    = (int*)(xwb + (size_t)N_EDGES * 8);
    int* cursorW = (int*)(xwb + (size_t)N_EDGES * 8 + (size_t)NBUCK * 4);

    u16* xbf = (u16*)d_out;  // d_out doubles as bf16-x scratch, then h

    detect_kernel<<<1, 64, 0, stream>>>((const u32*)x, ei, flags);
    hipMemsetAsync(cntW, 0, (size_t)NBUCK * 4, stream);
    count_convert<<<(N_EDGES + 255) / 256, 256, 0, stream>>>(ei, cntW, src32, dst32, flags);
    deg_dis<<<(N_NODES + 255) / 256, 256, 0, stream>>>(cntW, dis);
    scan_block_sums<<<SCAN_GRID_W, SCAN_B, 0, stream>>>(cntW, bsum, NBUCK);
    scan_bsum_big<<<1, 1024, 0, stream>>>(bsum);
    scan_final_w<<<SCAN_GRID_W, SCAN_B, 0, stream>>>(cntW, bsum, rowptrW, cursorW, NBUCK);
    for (int p = 0; p < NPASS; ++p)
        fill_csr_pass<<<(N_EDGES + 255) / 256, 256, 0, stream>>>(src32, dst32, cursorW,
                                                                 colidx, p * WIN);
    convert_x<<<(N_NODES * DIM + 255) / 256, 256, 0, stream>>>(x, xbf, flags);

    // layer 1
    transpose_w<<<DIM, DIM, 0, stream>>>(W1, Wt, flags);
    gemm_mfma<<<N_NODES / 16, 256, 0, stream>>>(xbf, Wt, dis, xw);
    aggregate<<<AGG_GRID, 256, 0, stream>>>(xw, rowptrW, colidx, dis, b1, d_out, flags, 0);

    // layer 2
    transpose_w<<<DIM, DIM, 0, stream>>>(W2, Wt, flags);
    gemm_mfma<<<N_NODES / 16, 256, 0, stream>>>((const u16*)d_out, Wt, dis, xw);
    aggregate<<<AGG_GRID, 256, 0, stream>>>(xw, rowptrW, colidx, dis, b2, d_out, flags, 1);
}